// Round 15
// baseline (166.909 us; speedup 1.0000x reference)
//
#include <hip/hip_runtime.h>
#include <stdint.h>

#define SEQ 4096
#define DM 768
#define NH 12
#define HD 64

typedef unsigned short u16;
typedef short short8 __attribute__((ext_vector_type(8)));
typedef float floatx4 __attribute__((ext_vector_type(4)));
typedef float floatx16 __attribute__((ext_vector_type(16)));

__device__ inline u16 f2b(float f) {
  union { float f; uint32_t u; } v; v.f = f;
  uint32_t u = v.u;
  return (u16)((u + 0x7fffu + ((u >> 16) & 1u)) >> 16);
}

__device__ inline float b2f(u16 x) {
  union { uint32_t u; float f; } v; v.u = ((uint32_t)x) << 16;
  return v.f;
}

#if defined(__has_builtin)
#if __has_builtin(__builtin_amdgcn_cvt_pk_bf16_f32)
#define HAVE_PK_BF16 1
#endif
#endif

// pack two fp32 -> two bf16 (RNE) in one dword.
// gfx950 has NO cvt_pk builtin (learn_hip m240) -> single-instruction asm.
__device__ inline uint32_t pk_bf16(float a, float b) {
#ifdef HAVE_PK_BF16
  typedef __bf16 bf16x2_t __attribute__((ext_vector_type(2)));
  union { bf16x2_t v; uint32_t u; } c;
  c.v = __builtin_amdgcn_cvt_pk_bf16_f32(a, b);
  return c.u;
#else
  uint32_t r;
  asm("v_cvt_pk_bf16_f32 %0, %1, %2" : "=v"(r) : "v"(a), "v"(b));
  return r;
#endif
}

// v_permlane32_swap_b32: a <- {a[0:31], b[0:31]}, b <- {a[32:63], b[32:63]}
__device__ inline void pl32swap(uint32_t& a, uint32_t& b) {
  asm("v_permlane32_swap_b32 %0, %1" : "+v"(a), "+v"(b));
}

__device__ inline void load_lds16(const void* g, void* l) {
  __builtin_amdgcn_global_load_lds(
      (const __attribute__((address_space(1))) uint32_t*)g,
      (__attribute__((address_space(3))) uint32_t*)l, 16, 0, 0);
}

// ---------------- fp32 -> bf16 conversion of X and the 4 weight matrices ----
__global__ __launch_bounds__(256) void convert_all(
    const float* __restrict__ X, const float* __restrict__ Wq,
    const float* __restrict__ Wk, const float* __restrict__ Wv,
    const float* __restrict__ Wo,
    u16* __restrict__ Xb, u16* __restrict__ Wqb, u16* __restrict__ Wkb,
    u16* __restrict__ Wvb, u16* __restrict__ Wob) {
  int t = blockIdx.x * 256 + threadIdx.x;   // each thread: 4 floats
  const int NX = SEQ * DM / 4;              // 786432
  const int NW = DM * DM / 4;               // 147456
  const float* src; u16* dst; int off;
  if (t < NX)               { src = X;  dst = Xb;  off = t; }
  else if (t < NX + NW)     { src = Wq; dst = Wqb; off = t - NX; }
  else if (t < NX + 2 * NW) { src = Wk; dst = Wkb; off = t - NX - NW; }
  else if (t < NX + 3 * NW) { src = Wv; dst = Wvb; off = t - NX - 2 * NW; }
  else if (t < NX + 4 * NW) { src = Wo; dst = Wob; off = t - NX - 3 * NW; }
  else return;
  float4 v = *(const float4*)(src + (size_t)off * 4);
  uint2 o;
  o.x = pk_bf16(v.x, v.y);
  o.y = pk_bf16(v.z, v.w);
  *(uint2*)(dst + (size_t)off * 4) = o;
}

// ---------------- QKV projection GEMM (128x128 tiles, BK=64, SINGLE-buf) ----
// m97 core (4 waves x 64x64 sub-tile, 4x4 16x16x32 frags, global_load_lds-16,
// XOR-swizzled LDS), single-buffered: LDS 34KB, launch_bounds(256,3) ->
// 3 blocks/CU. 576 blocks, XCD-chunked swizzle (576%8==0).
// C[s,j] = sum_k X[s,k] * W[j,k] + b[j]
// Q out: [h][s][d] scaled by 0.125*log2e ; K out: [h][s][d] ; V out: [h][d][s]
__global__ __launch_bounds__(256, 3) void gemm_qkv(
    const u16* __restrict__ Xb,
    const u16* __restrict__ Wqb, const u16* __restrict__ Wkb,
    const u16* __restrict__ Wvb,
    const float* __restrict__ bq, const float* __restrict__ bk,
    const float* __restrict__ bv,
    u16* __restrict__ Qh, u16* __restrict__ Kh, u16* __restrict__ VtG) {
  // XCD-chunked bijection: p -> wg so wg-contiguous chunks land per XCD.
  const int p = blockIdx.x;               // 576 blocks
  const int wg = (p & 7) * 72 + (p >> 3);
  const int mb = wg / 18, nz = wg % 18;
  const int z = nz / 6;                   // 0=Q, 1=K, 2=V
  const int n0 = (nz % 6) * 128;
  const int m0 = mb * 128;

  const u16* W; const float* bias;
  if (z == 0)      { W = Wqb; bias = bq; }
  else if (z == 1) { W = Wkb; bias = bk; }
  else             { W = Wvb; bias = bv; }

  __shared__ u16 smem[17408];             // 34KB: A[8192]+B[8192]; ep 128x136
  u16* As = smem;
  u16* Bs = smem + 8192;

  const int tid = threadIdx.x;
  const int wave = tid >> 6, lane = tid & 63;
  const int g = lane >> 4, ln = lane & 15;
  const int wm = (wave & 1) * 64, wn = (wave >> 1) * 64;
  const int srow = lane >> 3;
  const int schunk = (lane & 7) ^ srow;   // LDS[row][c] = G[row][c^(row&7)]
  const int swz = ln & 7;

  floatx4 acc[4][4] = {};

  auto stage = [&](int k0) {
#pragma unroll
    for (int i = 0; i < 4; ++i) {
      int u = wave * 4 + i;               // 16 units x 8 rows = 128 rows
      load_lds16(Xb + (size_t)(m0 + u * 8 + srow) * DM + k0 + schunk * 8,
                 As + u * 512);
      load_lds16(W + (size_t)(n0 + u * 8 + srow) * DM + k0 + schunk * 8,
                 Bs + u * 512);
    }
  };

  stage(0);

  for (int kt = 0; kt < 12; ++kt) {
    __syncthreads();          // stage landed (vmcnt(0) drained by compiler)
#pragma unroll
    for (int kh = 0; kh < 2; ++kh) {
      short8 af[4], bf[4];
#pragma unroll
      for (int mi = 0; mi < 4; ++mi)
        af[mi] = *(const short8*)(As + (wm + mi * 16 + ln) * 64 +
                                  ((kh * 4 + g) ^ swz) * 8);
#pragma unroll
      for (int ni = 0; ni < 4; ++ni)
        bf[ni] = *(const short8*)(Bs + (wn + ni * 16 + ln) * 64 +
                                  ((kh * 4 + g) ^ swz) * 8);
#pragma unroll
      for (int mi = 0; mi < 4; ++mi)
#pragma unroll
        for (int ni = 0; ni < 4; ++ni)
          acc[mi][ni] = __builtin_amdgcn_mfma_f32_16x16x32_bf16(
              af[mi], bf[ni], acc[mi][ni], 0, 0, 0);
    }
    __syncthreads();          // all reads done; safe to overwrite
    if (kt < 11) stage((kt + 1) * 64);
  }

  const float qscale = 0.125f * 1.44269504089f;  // softmax scale * log2(e)
  const int hh0 = n0 >> 6;                       // first of 2 heads in n-tile
  u16* ep = smem;   // reuse as 128x136 epilogue tile (last sync already done)

  if (z == 2) {
    // transposed tile T[dcol 0..127][row=s 0..127], stride 136
#pragma unroll
    for (int mi = 0; mi < 4; ++mi) {
      int row0 = wm + mi * 16 + g * 4;           // s-local
#pragma unroll
      for (int ni = 0; ni < 4; ++ni) {
        int col = wn + ni * 16 + ln;             // d-local (0..127)
        float b = bias[n0 + col];
        uint2 o;
        o.x = pk_bf16(acc[mi][ni][0] + b, acc[mi][ni][1] + b);
        o.y = pk_bf16(acc[mi][ni][2] + b, acc[mi][ni][3] + b);
        *(uint2*)(ep + col * 136 + row0) = o;
      }
    }
    __syncthreads();
#pragma unroll
    for (int t = 0; t < 8; ++t) {
      int unit = tid + t * 256;            // 2048 units = 128 dcols x 16 chunks
      int dcol = unit >> 4, ch = unit & 15;
      int head = hh0 + (dcol >> 6), d = dcol & 63;
      short8 v = *(const short8*)(ep + dcol * 136 + ch * 8);
      *(short8*)(VtG + ((size_t)(head * 64 + d)) * SEQ + m0 + ch * 8) = v;
    }
  } else {
    u16* out = (z == 0) ? Qh : Kh;
    float cs = (z == 0) ? qscale : 1.0f;
    // normal tile [row=s 0..127][col 0..127], stride 136
#pragma unroll
    for (int mi = 0; mi < 4; ++mi) {
      int row0 = wm + mi * 16 + g * 4;
#pragma unroll
      for (int ni = 0; ni < 4; ++ni) {
        int col = wn + ni * 16 + ln;
        float b = bias[n0 + col];
        uint32_t w0 = pk_bf16((acc[mi][ni][0] + b) * cs, (acc[mi][ni][1] + b) * cs);
        uint32_t w1 = pk_bf16((acc[mi][ni][2] + b) * cs, (acc[mi][ni][3] + b) * cs);
        ep[(row0 + 0) * 136 + col] = (u16)w0;
        ep[(row0 + 1) * 136 + col] = (u16)(w0 >> 16);
        ep[(row0 + 2) * 136 + col] = (u16)w1;
        ep[(row0 + 3) * 136 + col] = (u16)(w1 >> 16);
      }
    }
    __syncthreads();
#pragma unroll
    for (int t = 0; t < 8; ++t) {
      int unit = tid + t * 256;            // 2048 units = 128 rows x 16 chunks
      int row = unit >> 4, ch = unit & 15;
      int head = hh0 + (ch >> 3), d0 = (ch & 7) * 8;
      short8 v = *(const short8*)(ep + row * 136 + ch * 8);
      *(short8*)(out + ((size_t)head * SEQ + m0 + row) * HD + d0) = v;
    }
  }
}

// ---------------- flash attention (causal), fixed-max softmax --------------
// block = (h, chunk-of-(qB,ci)): 128 q rows x up to CHUNK=8 key-tiles.
// 1728 blocks (6.75/CU spatial >> 3/CU cap -> sustained 12 waves/CU).
// K/V in a 3-ring LDS (48KB), prefetch depth 2, COUNTED s_waitcnt vmcnt(4)
// + raw s_barrier (T4: never drain to 0 in-loop). This completes the 2x2
// factorial: R3 tested depth-2 alone (occupancy-capped, null), R5 tested
// more-blocks alone (depth-1, null); this is both together.
// 4 waves x 32 q (32x32x16 MFMA). XCD head-affinity (each XCD ~2 heads).
// S^T = K Q^T; P^T built in registers via cvt_pk_bf16 + permlane32_swap.
// Fixed-max softmax (M0 folded into acc init). qB<4 (single-partial)
// writes normalized O directly to Ob; others write RAW partials + l.
#define CHUNK 8
#define M0 40.0f
__global__ __launch_bounds__(256, 3) void attn_chunk(
    const u16* __restrict__ Qh, const u16* __restrict__ Kh,
    const u16* __restrict__ VtG, u16* __restrict__ Opart,
    float* __restrict__ Lp, u16* __restrict__ Ob) {
  // ---- XCD-affine decode: p in [0,1728) -> (h in [0,12), j in [0,144)).
  // 1728 = 24*72; qq=3*(p%8)+((p%24)>>3) pins each head-slot pair to one XCD.
  const int p = blockIdx.y * NH + blockIdx.x;
  const int slot = p % 24, cyc = p / 24;
  const int qq = 3 * (slot & 7) + (slot >> 3);
  const int h = qq >> 1;
  const int j = cyc * 2 + (qq & 1);       // 0 = dispatched first
  // j -> (qB, ci), heavy-first. Light-first rank r; qB-group g=qB>>2 has
  // g+1 chunks; group g occupies r in [2g(g+1), 2(g+1)(g+2)).
  const int r = 143 - j;
  int g = 0;
#pragma unroll
  for (int t = 1; t < 8; ++t)
    if (2 * t * (t + 1) <= r) g = t;
  const int gp1 = g + 1;
  const int rr = r - 2 * g * gp1;
  const int dq = rr / gp1;
  const int qB = 4 * g + dq;
  const int ci = rr - dq * gp1;
  const int kb0 = ci * CHUNK;
  const int kb1 = min(kb0 + CHUNK, 2 * qB + 2);
  const int n_part = gp1;                    // partials for this (h,qB): 1..8
  // compact partial slot: cum(qB) = (g+1)*(2g + (qB&3)), 144 slots per head
  const int slot2 = h * 144 + gp1 * (2 * g + (qB & 3)) + ci;

  const int tid = threadIdx.x, wave = tid >> 6, lane = tid & 63;
  const int hi = lane >> 5, lq = lane & 31;
  const int q0 = qB * 128;
  const int qwave = q0 + wave * 32;       // wave's min q row
  const int srow = lane >> 3;
  const int schunk = (lane & 7) ^ srow;
  const int rsw = lane & 7;               // read swizzle: row&7 == lane&7

  __shared__ u16 Ks[3 * 4096];      // [ring][key][d], chunk-swizzled
  __shared__ u16 Vt[3 * 4096];      // [ring][d][key], chunk-swizzled

  // Q as B-operand frags: lane holds Q[q=qwave+lq][d = s*16 + hi*8 + jj]
  const int qglob = qwave + lq;
  const u16* Qbase = Qh + ((size_t)h * SEQ + qglob) * HD;
  short8 aq[4];
#pragma unroll
  for (int s = 0; s < 4; ++s)
    aq[s] = *(const short8*)(Qbase + s * 16 + hi * 8);

  // oacc[dblk]: O^T[d = dblk*32 + (r&3)+8*(r>>2)+4*hi][q = lq]
  floatx16 oacc[2] = {};
  floatx4 lacc = {};                // per-lane partial row sums

  const size_t kbase = (size_t)h * SEQ * HD;
  const size_t vbase = (size_t)h * 64 * SEQ;

  // stage one 64-key K+V tile into ring slot (4 gload_lds/wave -> vmcnt +4)
  auto stage = [&](int kbIdx, int buf) {
#pragma unroll
    for (int i = 0; i < 2; ++i) {
      int u = wave * 2 + i;
      load_lds16(Kh + kbase + (size_t)(kbIdx * 64 + u * 8 + srow) * HD + schunk * 8,
                 Ks + buf * 4096 + u * 512);
      load_lds16(VtG + vbase + (size_t)(u * 8 + srow) * SEQ + kbIdx * 64 + schunk * 8,
                 Vt + buf * 4096 + u * 512);
    }
  };

  // prologue: fill 2 tiles ahead
  stage(kb0, 0);
  if (kb0 + 1 < kb1) stage(kb0 + 1, 1);

  for (int kb = kb0; kb < kb1; ++kb) {
    const int cur = (kb - kb0) % 3;
    // counted wait: outstanding = kb's 4 (oldest) + kb+1's 4 (if issued).
    // vmcnt(4) retires exactly kb's; kb+1's stay in flight across the
    // barrier. Drain to 0 only on the final tile.
    if (kb + 1 < kb1) asm volatile("s_waitcnt vmcnt(4)" ::: "memory");
    else              asm volatile("s_waitcnt vmcnt(0)" ::: "memory");
    __builtin_amdgcn_s_barrier();
    // prefetch kb+2 into the ring slot last read at iter kb-1 (ordered by
    // the barrier above).
    if (kb + 2 < kb1) stage(kb + 2, (cur + 2) % 3);

    const u16* Kc = Ks + cur * 4096;
    const u16* Vc = Vt + cur * 4096;

    // skip tiles entirely above this wave's diagonal (uniform branch)
    if (kb * 64 > qwave + 31) continue;

    // S^T = K Q^T : st[kblk] holds S^T[key=kb*64+kblk*32+(r&3)+8*(r>>2)+4*hi][q=lq]
    // accumulator pre-seeded with -M0 so exp2 applies directly (no sub pass)
    floatx16 st[2];
#pragma unroll
    for (int kblk = 0; kblk < 2; ++kblk)
#pragma unroll
      for (int r2 = 0; r2 < 16; ++r2) st[kblk][r2] = -M0;
    __builtin_amdgcn_s_setprio(1);
#pragma unroll
    for (int s = 0; s < 4; ++s)
#pragma unroll
      for (int kblk = 0; kblk < 2; ++kblk) {
        short8 kf = *(const short8*)(Kc + (kblk * 32 + lq) * 64 +
                                     ((s * 2 + hi) ^ rsw) * 8);
        st[kblk] = __builtin_amdgcn_mfma_f32_32x32x16_bf16(kf, aq[s], st[kblk],
                                                           0, 0, 0);
      }
    __builtin_amdgcn_s_setprio(0);

    if (kb * 64 + 63 > qwave) {  // tile straddles the diagonal for this wave
#pragma unroll
      for (int kblk = 0; kblk < 2; ++kblk)
#pragma unroll
        for (int r2 = 0; r2 < 16; ++r2) {
          int key = kb * 64 + kblk * 32 + (r2 & 3) + 8 * (r2 >> 2) + 4 * hi;
          if (key > qglob) st[kblk][r2] = -1e30f;
        }
    }

    // fixed-max softmax + pack: w[kblk][i] = bf16x2(p[2i], p[2i+1])
    uint32_t w[2][8];
#pragma unroll
    for (int kblk = 0; kblk < 2; ++kblk) {
#pragma unroll
      for (int r2 = 0; r2 < 16; ++r2)
        st[kblk][r2] = __builtin_amdgcn_exp2f(st[kblk][r2]);
#pragma unroll
      for (int r2 = 0; r2 < 4; ++r2)
        lacc[r2] += st[kblk][r2] + st[kblk][4 + r2] + st[kblk][8 + r2] +
                    st[kblk][12 + r2];
#pragma unroll
      for (int i = 0; i < 8; ++i)
        w[kblk][i] = pk_bf16(st[kblk][2 * i], st[kblk][2 * i + 1]);
    }

    // O^T += V^T P^T : P^T B-frag per k-step built via 2 permlane swaps.
    // lane needs P^T[key = ks*16 + hi*8 + jj][q=lq]:
    //   hi=0: dwords {own w[b+0], own w[b+1], partner w[b+0], partner w[b+1]}
    //   hi=1: dwords {partner w[b+2], partner w[b+3], own w[b+2], own w[b+3]}
    // permlane32_swap(a=w[b+i], b=w[b+2+i]) yields exactly dword i (new a)
    // and dword 2+i (new b) for ALL lanes.
    __builtin_amdgcn_s_setprio(1);
#pragma unroll
    for (int ks = 0; ks < 4; ++ks) {
      const int kblk = ks >> 1, base = (ks & 1) * 4;
      uint32_t d0 = w[kblk][base + 0], d2 = w[kblk][base + 2];
      uint32_t d1 = w[kblk][base + 1], d3 = w[kblk][base + 3];
      pl32swap(d0, d2);
      pl32swap(d1, d3);
      union { uint32_t u[4]; short8 s; } bp;
      bp.u[0] = d0; bp.u[1] = d1; bp.u[2] = d2; bp.u[3] = d3;
#pragma unroll
      for (int dblk = 0; dblk < 2; ++dblk) {
        short8 vf = *(const short8*)(Vc + (dblk * 32 + lq) * 64 +
                                     ((ks * 2 + hi) ^ rsw) * 8);
        oacc[dblk] = __builtin_amdgcn_mfma_f32_32x32x16_bf16(vf, bp.s, oacc[dblk],
                                                             0, 0, 0);
      }
    }
    __builtin_amdgcn_s_setprio(0);
  }

  // final l reduction: in-lane 4 -> 1, then across the two lane halves
  float l_i = lacc[0] + lacc[1] + lacc[2] + lacc[3];
  l_i += __shfl_xor(l_i, 32);

  int qloc = wave * 32 + lq;

  if (n_part == 1) {
    // single chunk (qB<4): normalized O straight to Ob [s][dm]
    float inv = 1.f / l_i;
    u16* dst = Ob + (size_t)(q0 + qloc) * DM + h * HD;
#pragma unroll
    for (int dblk = 0; dblk < 2; ++dblk)
#pragma unroll
      for (int qd = 0; qd < 4; ++qd) {
        uint2 o;
        o.x = pk_bf16(oacc[dblk][qd * 4 + 0] * inv, oacc[dblk][qd * 4 + 1] * inv);
        o.y = pk_bf16(oacc[dblk][qd * 4 + 2] * inv, oacc[dblk][qd * 4 + 3] * inv);
        *(uint2*)(dst + dblk * 32 + qd * 8 + hi * 4) = o;
      }
    return;
  }

  // multi-chunk: RAW partial O [q][d] bf16 + l per q (merge does sum x 1/L)
  u16* Op = Opart + (size_t)slot2 * 8192 + qloc * 64;
#pragma unroll
  for (int dblk = 0; dblk < 2; ++dblk)
#pragma unroll
    for (int qd = 0; qd < 4; ++qd) {
      uint2 o;
      o.x = pk_bf16(oacc[dblk][qd * 4 + 0], oacc[dblk][qd * 4 + 1]);
      o.y = pk_bf16(oacc[dblk][qd * 4 + 2], oacc[dblk][qd * 4 + 3]);
      *(uint2*)(Op + dblk * 32 + qd * 8 + hi * 4) = o;
    }
  if (hi == 0) Lp[(size_t)slot2 * 128 + qloc] = l_i;
}

// ---------------- merge raw partials -> Ob [s][dm] bf16 (qB >= 4 only) -----
// all partials share max M0 and are unnormalized -> Ob = (sum_i part_i)/L.
// qB<4 rows were written directly by attn_chunk. grid (NH, 28).
__global__ __launch_bounds__(256) void attn_merge(
    const u16* __restrict__ Opart, const float* __restrict__ Lp,
    u16* __restrict__ Ob) {
  const int h = blockIdx.x, qB = 4 + blockIdx.y;
  const int g = qB >> 2;
  const int n = g + 1;                    // partials per (h,qB): 2..8
  const int base = h * 144 + (g + 1) * (2 * g + (qB & 3));
  const int q = threadIdx.x >> 1;
  const int d0 = (threadIdx.x & 1) * 32;

  float L = 0.f;
  for (int i = 0; i < n; ++i) L += Lp[(size_t)(base + i) * 128 + q];
  float invL = 1.f / L;

  float acc[32];
#pragma unroll
  for (int jj = 0; jj < 32; ++jj) acc[jj] = 0.f;
  for (int i = 0; i < n; ++i) {
    const u16* src = Opart + (size_t)(base + i) * 8192 + q * 64 + d0;
#pragma unroll
    for (int c = 0; c < 4; ++c) {
      short8 a = ((const short8*)src)[c];
#pragma unroll
      for (int jj = 0; jj < 8; ++jj) acc[c * 8 + jj] += b2f((u16)a[jj]);
    }
  }

  u16* dst = Ob + (size_t)(qB * 128 + q) * DM + h * HD + d0;
#pragma unroll
  for (int c = 0; c < 4; ++c) {
    uint4 o;
    o.x = pk_bf16(acc[c * 8 + 0] * invL, acc[c * 8 + 1] * invL);
    o.y = pk_bf16(acc[c * 8 + 2] * invL, acc[c * 8 + 3] * invL);
    o.z = pk_bf16(acc[c * 8 + 4] * invL, acc[c * 8 + 5] * invL);
    o.w = pk_bf16(acc[c * 8 + 6] * invL, acc[c * 8 + 7] * invL);
    ((uint4*)dst)[c] = o;
  }
}

// ---------------- output projection GEMM (fp32 out, 64x64, dbuf) -----------
__global__ __launch_bounds__(256) void gemm_out(
    const u16* __restrict__ Ab, const u16* __restrict__ Wob,
    const float* __restrict__ bo, float* __restrict__ Cout) {
  __shared__ u16 smem[16384];   // A: [2][4096], B: [2][4096]

  const int tid = threadIdx.x;
  const int wave = tid >> 6, lane = tid & 63;
  const int g = lane >> 4, ln = lane & 15;
  const int m0 = blockIdx.y * 64, n0 = blockIdx.x * 64;
  const int wm = (wave & 1) * 32, wn = (wave >> 1) * 32;
  const int srow = lane >> 3;
  const int schunk = (lane & 7) ^ srow;
  const int swz = ln & 7;

  floatx4 acc[2][2] = {};

#pragma unroll
  for (int i = 0; i < 2; ++i) {
    int u = wave * 2 + i;
    load_lds16(Ab + (size_t)(m0 + u * 8 + srow) * DM + schunk * 8, smem + u * 512);
    load_lds16(Wob + (size_t)(n0 + u * 8 + srow) * DM + schunk * 8,
               smem + 8192 + u * 512);
  }

  for (int kt = 0; kt < 12; ++kt) {
    const int cur = kt & 1;
    __syncthreads();
    if (kt < 11) {
      const int k0 = (kt + 1) * 64, nb = cur ^ 1;
#pragma unroll
      for (int i = 0; i < 2; ++i) {
        int u = wave * 2 + i;
        load_lds16(Ab + (size_t)(m0 + u * 8 + srow) * DM + k0 + schunk * 8,
                   smem + nb * 4096 + u * 512);
        load_lds16(Wob + (size_t)(n0 + u * 8 + srow) * DM + k0 + schunk * 8,
                   smem + 8192 + nb * 4096 + u * 512);
      }
    }
    const u16* Ac = smem + cur * 4096;
    const u16* Bc = smem + 8192 + cur * 4096;
    short8 af[2][2], bf[2][2];
#pragma unroll
    for (int mi = 0; mi < 2; ++mi)
#pragma unroll
      for (int kh = 0; kh < 2; ++kh)
        af[mi][kh] = *(const short8*)(Ac + (wm + mi * 16 + ln) * 64 +
                                      ((kh * 4 + g) ^ swz) * 8);
#pragma unroll
    for (int ni = 0; ni < 2; ++ni)
#pragma unroll
      for (int kh = 0; kh < 2; ++kh)
        bf[ni][kh] = *(const short8*)(Bc + (wn + ni * 16 + ln) * 64 +
                                      ((kh * 4 + g) ^ swz) * 8);
#pragma unroll
    for (int kh = 0; kh < 2; ++kh)
#pragma unroll
      for (int mi = 0; mi < 2; ++mi)
#pragma unroll
        for (int ni = 0; ni < 2; ++ni)
          acc[mi][ni] = __builtin_amdgcn_mfma_f32_16x16x32_bf16(
              af[mi][kh], bf[ni][kh], acc[mi][ni], 0, 0, 0);
  }

#pragma unroll
  for (int mi = 0; mi < 2; ++mi) {
    int row = m0 + wm + mi * 16 + g * 4;
#pragma unroll
    for (int ni = 0; ni < 2; ++ni) {
      int col = n0 + wn + ni * 16 + ln;
      float b = bo[col];
#pragma unroll
      for (int r = 0; r < 4; ++r)
        Cout[(size_t)(row + r) * DM + col] = acc[mi][ni][r] + b;
    }
  }
}

extern "C" void kernel_launch(void* const* d_in, const int* in_sizes, int n_in,
                              void* d_out, int out_size, void* d_ws, size_t ws_size,
                              hipStream_t stream) {
  const float* X  = (const float*)d_in[0];
  const float* Wq = (const float*)d_in[1];
  const float* bq = (const float*)d_in[2];
  const float* Wk = (const float*)d_in[3];
  const float* bk = (const float*)d_in[4];
  const float* Wv = (const float*)d_in[5];
  const float* bv = (const float*)d_in[6];
  const float* Wo = (const float*)d_in[7];
  const float* bo = (const float*)d_in[8];
  float* out = (float*)d_out;

  // Workspace layout with OVERLAY: Xb/Wqb/Wkb/Wvb are dead after gemm_qkv,
  // so Opart (28.3MB at CHUNK=8) reuses their region and beyond (ws is
  // 256MB; pointer arithmetic stays in-bounds).
  char* ws = (char*)d_ws;
  u16* Wob = (u16*)ws; ws += (size_t)DM * DM * 2;                 // 1.18MB
  u16* Qh  = (u16*)ws; ws += (size_t)NH * SEQ * HD * 2;           // 6.29MB
  u16* Kh  = (u16*)ws; ws += (size_t)NH * SEQ * HD * 2;           // 6.29MB
  u16* VtG = (u16*)ws; ws += (size_t)NH * SEQ * HD * 2;           // [h][d][s]
  u16* Ob  = (u16*)ws; ws += (size_t)SEQ * DM * 2;                // 6.29MB
  float* Lp = (float*)ws; ws += (size_t)NH * 144 * 128 * 4;       // 0.88MB
  char* ovl = ws;
  u16* Xb  = (u16*)ovl;
  u16* Wqb = Xb + (size_t)SEQ * DM;
  u16* Wkb = Wqb + (size_t)DM * DM;
  u16* Wvb = Wkb + (size_t)DM * DM;
  u16* Opart = (u16*)ovl;   // 12*144*128*64*2 = 28.3MB, after Xb/Wq/Wk/Wv die

  convert_all<<<5376, 256, 0, stream>>>(X, Wq, Wk, Wv, Wo, Xb, Wqb, Wkb, Wvb,
                                        Wob);

  gemm_qkv<<<576, 256, 0, stream>>>(Xb, Wqb, Wkb, Wvb, bq, bk, bv, Qh, Kh, VtG);

  dim3 ga(NH, 144);
  attn_chunk<<<ga, 256, 0, stream>>>(Qh, Kh, VtG, Opart, Lp, Ob);

  dim3 gm(NH, 28);
  attn_merge<<<gm, 256, 0, stream>>>(Opart, Lp, Ob);

  dim3 go(DM / 64, SEQ / 64);
  gemm_out<<<go, 256, 0, stream>>>(Ob, Wob, bo, out);
}

// Round 16
// 161.888 us; speedup vs baseline: 1.0310x; 1.0310x over previous
//
#include <hip/hip_runtime.h>
#include <stdint.h>

#define SEQ 4096
#define DM 768
#define NH 12
#define HD 64

typedef unsigned short u16;
typedef short short8 __attribute__((ext_vector_type(8)));
typedef float floatx4 __attribute__((ext_vector_type(4)));
typedef float floatx16 __attribute__((ext_vector_type(16)));

__device__ inline u16 f2b(float f) {
  union { float f; uint32_t u; } v; v.f = f;
  uint32_t u = v.u;
  return (u16)((u + 0x7fffu + ((u >> 16) & 1u)) >> 16);
}

__device__ inline float b2f(u16 x) {
  union { uint32_t u; float f; } v; v.u = ((uint32_t)x) << 16;
  return v.f;
}

#if defined(__has_builtin)
#if __has_builtin(__builtin_amdgcn_cvt_pk_bf16_f32)
#define HAVE_PK_BF16 1
#endif
#endif

// pack two fp32 -> two bf16 (RNE) in one dword.
// gfx950 has NO cvt_pk builtin (learn_hip m240) -> single-instruction asm.
__device__ inline uint32_t pk_bf16(float a, float b) {
#ifdef HAVE_PK_BF16
  typedef __bf16 bf16x2_t __attribute__((ext_vector_type(2)));
  union { bf16x2_t v; uint32_t u; } c;
  c.v = __builtin_amdgcn_cvt_pk_bf16_f32(a, b);
  return c.u;
#else
  uint32_t r;
  asm("v_cvt_pk_bf16_f32 %0, %1, %2" : "=v"(r) : "v"(a), "v"(b));
  return r;
#endif
}

// v_permlane32_swap_b32: a <- {a[0:31], b[0:31]}, b <- {a[32:63], b[32:63]}
__device__ inline void pl32swap(uint32_t& a, uint32_t& b) {
  asm("v_permlane32_swap_b32 %0, %1" : "+v"(a), "+v"(b));
}

__device__ inline void load_lds16(const void* g, void* l) {
  __builtin_amdgcn_global_load_lds(
      (const __attribute__((address_space(1))) uint32_t*)g,
      (__attribute__((address_space(3))) uint32_t*)l, 16, 0, 0);
}

// ---------------- fp32 -> bf16 conversion of X and the 4 weight matrices ----
__global__ __launch_bounds__(256) void convert_all(
    const float* __restrict__ X, const float* __restrict__ Wq,
    const float* __restrict__ Wk, const float* __restrict__ Wv,
    const float* __restrict__ Wo,
    u16* __restrict__ Xb, u16* __restrict__ Wqb, u16* __restrict__ Wkb,
    u16* __restrict__ Wvb, u16* __restrict__ Wob) {
  int t = blockIdx.x * 256 + threadIdx.x;   // each thread: 4 floats
  const int NX = SEQ * DM / 4;              // 786432
  const int NW = DM * DM / 4;               // 147456
  const float* src; u16* dst; int off;
  if (t < NX)               { src = X;  dst = Xb;  off = t; }
  else if (t < NX + NW)     { src = Wq; dst = Wqb; off = t - NX; }
  else if (t < NX + 2 * NW) { src = Wk; dst = Wkb; off = t - NX - NW; }
  else if (t < NX + 3 * NW) { src = Wv; dst = Wvb; off = t - NX - 2 * NW; }
  else if (t < NX + 4 * NW) { src = Wo; dst = Wob; off = t - NX - 3 * NW; }
  else return;
  float4 v = *(const float4*)(src + (size_t)off * 4);
  uint2 o;
  o.x = pk_bf16(v.x, v.y);
  o.y = pk_bf16(v.z, v.w);
  *(uint2*)(dst + (size_t)off * 4) = o;
}

// ---------------- QKV projection GEMM (128x128 tiles, BK=64, SINGLE-buf) ----
// m97 core (4 waves x 64x64 sub-tile, 4x4 16x16x32 frags, global_load_lds-16,
// XOR-swizzled LDS), single-buffered: LDS 34KB, launch_bounds(256,3) ->
// 3 blocks/CU -> all 576 blocks co-resident (one generation).
// C[s,j] = sum_k X[s,k] * W[j,k] + b[j]
// Q out: [h][s][d] scaled by 0.125*log2e ; K out: [h][s][d] ; V out: [h][d][s]
__global__ __launch_bounds__(256, 3) void gemm_qkv(
    const u16* __restrict__ Xb,
    const u16* __restrict__ Wqb, const u16* __restrict__ Wkb,
    const u16* __restrict__ Wvb,
    const float* __restrict__ bq, const float* __restrict__ bk,
    const float* __restrict__ bv,
    u16* __restrict__ Qh, u16* __restrict__ Kh, u16* __restrict__ VtG) {
  // XCD-chunked bijection: p -> wg so wg-contiguous chunks land per XCD.
  const int p = blockIdx.x;               // 576 blocks
  const int wg = (p & 7) * 72 + (p >> 3);
  const int mb = wg / 18, nz = wg % 18;
  const int z = nz / 6;                   // 0=Q, 1=K, 2=V
  const int n0 = (nz % 6) * 128;
  const int m0 = mb * 128;

  const u16* W; const float* bias;
  if (z == 0)      { W = Wqb; bias = bq; }
  else if (z == 1) { W = Wkb; bias = bk; }
  else             { W = Wvb; bias = bv; }

  __shared__ u16 smem[17408];             // 34KB: A[8192]+B[8192]; ep 128x136
  u16* As = smem;
  u16* Bs = smem + 8192;

  const int tid = threadIdx.x;
  const int wave = tid >> 6, lane = tid & 63;
  const int g = lane >> 4, ln = lane & 15;
  const int wm = (wave & 1) * 64, wn = (wave >> 1) * 64;
  const int srow = lane >> 3;
  const int schunk = (lane & 7) ^ srow;   // LDS[row][c] = G[row][c^(row&7)]
  const int swz = ln & 7;

  floatx4 acc[4][4] = {};

  auto stage = [&](int k0) {
#pragma unroll
    for (int i = 0; i < 4; ++i) {
      int u = wave * 4 + i;               // 16 units x 8 rows = 128 rows
      load_lds16(Xb + (size_t)(m0 + u * 8 + srow) * DM + k0 + schunk * 8,
                 As + u * 512);
      load_lds16(W + (size_t)(n0 + u * 8 + srow) * DM + k0 + schunk * 8,
                 Bs + u * 512);
    }
  };

  stage(0);

  for (int kt = 0; kt < 12; ++kt) {
    __syncthreads();          // stage landed (vmcnt(0) drained by compiler)
#pragma unroll
    for (int kh = 0; kh < 2; ++kh) {
      short8 af[4], bf[4];
#pragma unroll
      for (int mi = 0; mi < 4; ++mi)
        af[mi] = *(const short8*)(As + (wm + mi * 16 + ln) * 64 +
                                  ((kh * 4 + g) ^ swz) * 8);
#pragma unroll
      for (int ni = 0; ni < 4; ++ni)
        bf[ni] = *(const short8*)(Bs + (wn + ni * 16 + ln) * 64 +
                                  ((kh * 4 + g) ^ swz) * 8);
#pragma unroll
      for (int mi = 0; mi < 4; ++mi)
#pragma unroll
        for (int ni = 0; ni < 4; ++ni)
          acc[mi][ni] = __builtin_amdgcn_mfma_f32_16x16x32_bf16(
              af[mi], bf[ni], acc[mi][ni], 0, 0, 0);
    }
    __syncthreads();          // all reads done; safe to overwrite
    if (kt < 11) stage((kt + 1) * 64);
  }

  const float qscale = 0.125f * 1.44269504089f;  // softmax scale * log2(e)
  const int hh0 = n0 >> 6;                       // first of 2 heads in n-tile
  u16* ep = smem;   // reuse as 128x136 epilogue tile (last sync already done)

  if (z == 2) {
    // transposed tile T[dcol 0..127][row=s 0..127], stride 136
#pragma unroll
    for (int mi = 0; mi < 4; ++mi) {
      int row0 = wm + mi * 16 + g * 4;           // s-local
#pragma unroll
      for (int ni = 0; ni < 4; ++ni) {
        int col = wn + ni * 16 + ln;             // d-local (0..127)
        float b = bias[n0 + col];
        uint2 o;
        o.x = pk_bf16(acc[mi][ni][0] + b, acc[mi][ni][1] + b);
        o.y = pk_bf16(acc[mi][ni][2] + b, acc[mi][ni][3] + b);
        *(uint2*)(ep + col * 136 + row0) = o;
      }
    }
    __syncthreads();
#pragma unroll
    for (int t = 0; t < 8; ++t) {
      int unit = tid + t * 256;            // 2048 units = 128 dcols x 16 chunks
      int dcol = unit >> 4, ch = unit & 15;
      int head = hh0 + (dcol >> 6), d = dcol & 63;
      short8 v = *(const short8*)(ep + dcol * 136 + ch * 8);
      *(short8*)(VtG + ((size_t)(head * 64 + d)) * SEQ + m0 + ch * 8) = v;
    }
  } else {
    u16* out = (z == 0) ? Qh : Kh;
    float cs = (z == 0) ? qscale : 1.0f;
    // normal tile [row=s 0..127][col 0..127], stride 136
#pragma unroll
    for (int mi = 0; mi < 4; ++mi) {
      int row0 = wm + mi * 16 + g * 4;
#pragma unroll
      for (int ni = 0; ni < 4; ++ni) {
        int col = wn + ni * 16 + ln;
        float b = bias[n0 + col];
        uint32_t w0 = pk_bf16((acc[mi][ni][0] + b) * cs, (acc[mi][ni][1] + b) * cs);
        uint32_t w1 = pk_bf16((acc[mi][ni][2] + b) * cs, (acc[mi][ni][3] + b) * cs);
        ep[(row0 + 0) * 136 + col] = (u16)w0;
        ep[(row0 + 1) * 136 + col] = (u16)(w0 >> 16);
        ep[(row0 + 2) * 136 + col] = (u16)w1;
        ep[(row0 + 3) * 136 + col] = (u16)(w1 >> 16);
      }
    }
    __syncthreads();
#pragma unroll
    for (int t = 0; t < 8; ++t) {
      int unit = tid + t * 256;            // 2048 units = 128 rows x 16 chunks
      int row = unit >> 4, ch = unit & 15;
      int head = hh0 + (ch >> 3), d0 = (ch & 7) * 8;
      short8 v = *(const short8*)(ep + row * 136 + ch * 8);
      *(short8*)(out + ((size_t)head * SEQ + m0 + row) * HD + d0) = v;
    }
  }
}

// ---------------- flash attention (causal), fixed-max softmax --------------
// block = (h, chunk-of-(qB,ci)): 128 q rows x up to CHUNK=16 key-tiles.
// 960 blocks, 4 waves x 32 q each (32x32x16 MFMA), K/V double-buffered.
// XCD head-affinity: each XCD (p%8) sees ~2 heads -> K/V fits 4MB L2.
// S^T = K Q^T; P^T built in registers via cvt_pk_bf16 + permlane32_swap.
// Fixed-max softmax (M0 folded into MFMA accumulator init).
// qB<8 (single-partial) blocks write NORMALIZED O directly to Ob -- no
// Opart/Lp round-trip, no cross-block coordination. qB>=8 writes RAW
// partial O + l; attn_merge (qB>=8 only) does unweighted-sum x 1/L.
// NO cross-block sync (R9: device fences flush per-XCD L2, 3x slowdown).
// attn floor note: 44.3-47.4us across occupancy 17-31%, CHUNK 8/16,
// prefetch depth 1/2, counted vs drained vmcnt (R2-R15) -- the per-tile
// dependent chain (QK^T MFMA -> mask -> exp2(trans) -> pack -> permlane
// -> PV MFMA) is the floor at this block structure.
#define CHUNK 16
#define M0 40.0f
__global__ __launch_bounds__(256, 4) void attn_chunk(
    const u16* __restrict__ Qh, const u16* __restrict__ Kh,
    const u16* __restrict__ VtG, u16* __restrict__ Opart,
    float* __restrict__ Lp, u16* __restrict__ Ob) {
  // ---- XCD-affine decode: p in [0,960) -> (h in [0,12), j in [0,80)).
  // 960 = 24*40; qq=3*(p%8)+((p%24)>>3) pins each head-slot pair to one XCD.
  const int p = blockIdx.y * NH + blockIdx.x;
  const int slot = p % 24, cyc = p / 24;
  const int qq = 3 * (slot & 7) + (slot >> 3);
  const int h = qq >> 1;
  const int b = 79 - (cyc * 2 + (qq & 1));   // heavy blocks dispatched first
  int qB, ci;
  if (b < 8)       { qB = b;               ci = 0; }
  else if (b < 24) { int r = b - 8;  qB = 8 + (r >> 1); ci = r & 1; }
  else if (b < 48) { int r = b - 24; int d = r / 3; qB = 16 + d; ci = r - d * 3; }
  else             { int r = b - 48; qB = 24 + (r >> 2); ci = r & 3; }
  const int kb0 = ci * CHUNK;
  const int kb1 = min(kb0 + CHUNK, 2 * qB + 2);
  const int n_part = (qB >> 3) + 1;          // partials for this (h,qB): 1..4
  const int slot2 = (h * 32 + qB) * 4 + ci;

  const int tid = threadIdx.x, wave = tid >> 6, lane = tid & 63;
  const int hi = lane >> 5, lq = lane & 31;
  const int q0 = qB * 128;
  const int qwave = q0 + wave * 32;       // wave's min q row
  const int srow = lane >> 3;
  const int schunk = (lane & 7) ^ srow;
  const int rsw = lane & 7;               // read swizzle: row&7 == lane&7

  __shared__ u16 Ks[2 * 4096];      // [buf][key][d], chunk-swizzled
  __shared__ u16 Vt[2 * 4096];      // [buf][d][key], chunk-swizzled

  // Q as B-operand frags: lane holds Q[q=qwave+lq][d = s*16 + hi*8 + j]
  const int qglob = qwave + lq;
  const u16* Qbase = Qh + ((size_t)h * SEQ + qglob) * HD;
  short8 aq[4];
#pragma unroll
  for (int s = 0; s < 4; ++s)
    aq[s] = *(const short8*)(Qbase + s * 16 + hi * 8);

  // oacc[dblk]: O^T[d = dblk*32 + (r&3)+8*(r>>2)+4*hi][q = lq]
  floatx16 oacc[2] = {};
  floatx4 lacc = {};                // per-lane partial row sums

  const size_t kbase = (size_t)h * SEQ * HD;
  const size_t vbase = (size_t)h * 64 * SEQ;

  auto stage = [&](int kbIdx, int buf) {
#pragma unroll
    for (int i = 0; i < 2; ++i) {
      int u = wave * 2 + i;
      load_lds16(Kh + kbase + (size_t)(kbIdx * 64 + u * 8 + srow) * HD + schunk * 8,
                 Ks + buf * 4096 + u * 512);
      load_lds16(VtG + vbase + (size_t)(u * 8 + srow) * SEQ + kbIdx * 64 + schunk * 8,
                 Vt + buf * 4096 + u * 512);
    }
  };

  stage(kb0, 0);

  for (int kb = kb0; kb < kb1; ++kb) {
    const int cur = (kb - kb0) & 1;
    __syncthreads();   // drains vmcnt: buf[cur] landed; prior reads of buf[nxt] done
    if (kb + 1 < kb1) stage(kb + 1, cur ^ 1);

    const u16* Kc = Ks + cur * 4096;
    const u16* Vc = Vt + cur * 4096;

    // skip tiles entirely above this wave's diagonal (uniform branch)
    if (kb * 64 > qwave + 31) continue;

    // S^T = K Q^T : st[kblk] holds S^T[key=kb*64+kblk*32+(r&3)+8*(r>>2)+4*hi][q=lq]
    // accumulator pre-seeded with -M0 so exp2 applies directly (no sub pass)
    floatx16 st[2];
#pragma unroll
    for (int kblk = 0; kblk < 2; ++kblk)
#pragma unroll
      for (int r2 = 0; r2 < 16; ++r2) st[kblk][r2] = -M0;
    __builtin_amdgcn_s_setprio(1);
#pragma unroll
    for (int s = 0; s < 4; ++s)
#pragma unroll
      for (int kblk = 0; kblk < 2; ++kblk) {
        short8 kf = *(const short8*)(Kc + (kblk * 32 + lq) * 64 +
                                     ((s * 2 + hi) ^ rsw) * 8);
        st[kblk] = __builtin_amdgcn_mfma_f32_32x32x16_bf16(kf, aq[s], st[kblk],
                                                           0, 0, 0);
      }
    __builtin_amdgcn_s_setprio(0);

    if (kb * 64 + 63 > qwave) {  // tile straddles the diagonal for this wave
#pragma unroll
      for (int kblk = 0; kblk < 2; ++kblk)
#pragma unroll
        for (int r2 = 0; r2 < 16; ++r2) {
          int key = kb * 64 + kblk * 32 + (r2 & 3) + 8 * (r2 >> 2) + 4 * hi;
          if (key > qglob) st[kblk][r2] = -1e30f;
        }
    }

    // fixed-max softmax + pack: w[kblk][i] = bf16x2(p[2i], p[2i+1])
    uint32_t w[2][8];
#pragma unroll
    for (int kblk = 0; kblk < 2; ++kblk) {
#pragma unroll
      for (int r2 = 0; r2 < 16; ++r2)
        st[kblk][r2] = __builtin_amdgcn_exp2f(st[kblk][r2]);
#pragma unroll
      for (int r2 = 0; r2 < 4; ++r2)
        lacc[r2] += st[kblk][r2] + st[kblk][4 + r2] + st[kblk][8 + r2] +
                    st[kblk][12 + r2];
#pragma unroll
      for (int i = 0; i < 8; ++i)
        w[kblk][i] = pk_bf16(st[kblk][2 * i], st[kblk][2 * i + 1]);
    }

    // O^T += V^T P^T : P^T B-frag per k-step built via 2 permlane swaps.
    // lane needs P^T[key = ks*16 + hi*8 + jj][q=lq]:
    //   hi=0: dwords {own w[b+0], own w[b+1], partner w[b+0], partner w[b+1]}
    //   hi=1: dwords {partner w[b+2], partner w[b+3], own w[b+2], own w[b+3]}
    // permlane32_swap(a=w[b+i], b=w[b+2+i]) yields exactly dword i (new a)
    // and dword 2+i (new b) for ALL lanes.
    __builtin_amdgcn_s_setprio(1);
#pragma unroll
    for (int ks = 0; ks < 4; ++ks) {
      const int kblk = ks >> 1, base = (ks & 1) * 4;
      uint32_t d0 = w[kblk][base + 0], d2 = w[kblk][base + 2];
      uint32_t d1 = w[kblk][base + 1], d3 = w[kblk][base + 3];
      pl32swap(d0, d2);
      pl32swap(d1, d3);
      union { uint32_t u[4]; short8 s; } bp;
      bp.u[0] = d0; bp.u[1] = d1; bp.u[2] = d2; bp.u[3] = d3;
#pragma unroll
      for (int dblk = 0; dblk < 2; ++dblk) {
        short8 vf = *(const short8*)(Vc + (dblk * 32 + lq) * 64 +
                                     ((ks * 2 + hi) ^ rsw) * 8);
        oacc[dblk] = __builtin_amdgcn_mfma_f32_32x32x16_bf16(vf, bp.s, oacc[dblk],
                                                             0, 0, 0);
      }
    }
    __builtin_amdgcn_s_setprio(0);
  }

  // final l reduction: in-lane 4 -> 1, then across the two lane halves
  float l_i = lacc[0] + lacc[1] + lacc[2] + lacc[3];
  l_i += __shfl_xor(l_i, 32);

  int qloc = wave * 32 + lq;

  if (n_part == 1) {
    // single chunk: normalized O straight to Ob [s][dm] -- skips Opart/Lp
    float inv = 1.f / l_i;
    u16* dst = Ob + (size_t)(q0 + qloc) * DM + h * HD;
#pragma unroll
    for (int dblk = 0; dblk < 2; ++dblk)
#pragma unroll
      for (int qd = 0; qd < 4; ++qd) {
        uint2 o;
        o.x = pk_bf16(oacc[dblk][qd * 4 + 0] * inv, oacc[dblk][qd * 4 + 1] * inv);
        o.y = pk_bf16(oacc[dblk][qd * 4 + 2] * inv, oacc[dblk][qd * 4 + 3] * inv);
        *(uint2*)(dst + dblk * 32 + qd * 8 + hi * 4) = o;
      }
    return;
  }

  // multi-chunk: RAW partial O [q][d] bf16 + l per q (merge does sum x 1/L;
  // raw storage skips one rounding pass -- measured absmax 0.0044 vs 0.0078).
  u16* Op = Opart + (size_t)slot2 * 8192 + qloc * 64;
#pragma unroll
  for (int dblk = 0; dblk < 2; ++dblk)
#pragma unroll
    for (int qd = 0; qd < 4; ++qd) {
      uint2 o;
      o.x = pk_bf16(oacc[dblk][qd * 4 + 0], oacc[dblk][qd * 4 + 1]);
      o.y = pk_bf16(oacc[dblk][qd * 4 + 2], oacc[dblk][qd * 4 + 3]);
      *(uint2*)(Op + dblk * 32 + qd * 8 + hi * 4) = o;
    }
  if (hi == 0) Lp[(size_t)slot2 * 128 + qloc] = l_i;
}

// ---------------- merge raw partials -> Ob [s][dm] bf16 (qB >= 8 only) -----
// all partials share max M0 and are unnormalized -> Ob = (sum_i part_i)/L.
// qB<8 rows were written directly by attn_chunk. grid (NH, 24).
__global__ __launch_bounds__(256) void attn_merge(
    const u16* __restrict__ Opart, const float* __restrict__ Lp,
    u16* __restrict__ Ob) {
  const int h = blockIdx.x, qB = 8 + blockIdx.y;
  const int n = (qB >> 3) + 1;            // partials per (h,qB): 2..4
  const int base = (h * 32 + qB) * 4;
  const int q = threadIdx.x >> 1;
  const int d0 = (threadIdx.x & 1) * 32;

  float L = 0.f;
  for (int i = 0; i < n; ++i) L += Lp[(size_t)(base + i) * 128 + q];
  float invL = 1.f / L;

  float acc[32];
#pragma unroll
  for (int jj = 0; jj < 32; ++jj) acc[jj] = 0.f;
  for (int i = 0; i < n; ++i) {
    const u16* src = Opart + (size_t)(base + i) * 8192 + q * 64 + d0;
#pragma unroll
    for (int c = 0; c < 4; ++c) {
      short8 a = ((const short8*)src)[c];
#pragma unroll
      for (int jj = 0; jj < 8; ++jj) acc[c * 8 + jj] += b2f((u16)a[jj]);
    }
  }

  u16* dst = Ob + (size_t)(qB * 128 + q) * DM + h * HD + d0;
#pragma unroll
  for (int c = 0; c < 4; ++c) {
    uint4 o;
    o.x = pk_bf16(acc[c * 8 + 0] * invL, acc[c * 8 + 1] * invL);
    o.y = pk_bf16(acc[c * 8 + 2] * invL, acc[c * 8 + 3] * invL);
    o.z = pk_bf16(acc[c * 8 + 4] * invL, acc[c * 8 + 5] * invL);
    o.w = pk_bf16(acc[c * 8 + 6] * invL, acc[c * 8 + 7] * invL);
    ((uint4*)dst)[c] = o;
  }
}

// ---------------- output projection GEMM (fp32 out, 64x64, dbuf) -----------
__global__ __launch_bounds__(256) void gemm_out(
    const u16* __restrict__ Ab, const u16* __restrict__ Wob,
    const float* __restrict__ bo, float* __restrict__ Cout) {
  __shared__ u16 smem[16384];   // A: [2][4096], B: [2][4096]

  const int tid = threadIdx.x;
  const int wave = tid >> 6, lane = tid & 63;
  const int g = lane >> 4, ln = lane & 15;
  const int m0 = blockIdx.y * 64, n0 = blockIdx.x * 64;
  const int wm = (wave & 1) * 32, wn = (wave >> 1) * 32;
  const int srow = lane >> 3;
  const int schunk = (lane & 7) ^ srow;
  const int swz = ln & 7;

  floatx4 acc[2][2] = {};

#pragma unroll
  for (int i = 0; i < 2; ++i) {
    int u = wave * 2 + i;
    load_lds16(Ab + (size_t)(m0 + u * 8 + srow) * DM + schunk * 8, smem + u * 512);
    load_lds16(Wob + (size_t)(n0 + u * 8 + srow) * DM + schunk * 8,
               smem + 8192 + u * 512);
  }

  for (int kt = 0; kt < 12; ++kt) {
    const int cur = kt & 1;
    __syncthreads();
    if (kt < 11) {
      const int k0 = (kt + 1) * 64, nb = cur ^ 1;
#pragma unroll
      for (int i = 0; i < 2; ++i) {
        int u = wave * 2 + i;
        load_lds16(Ab + (size_t)(m0 + u * 8 + srow) * DM + k0 + schunk * 8,
                   smem + nb * 4096 + u * 512);
        load_lds16(Wob + (size_t)(n0 + u * 8 + srow) * DM + k0 + schunk * 8,
                   smem + 8192 + nb * 4096 + u * 512);
      }
    }
    const u16* Ac = smem + cur * 4096;
    const u16* Bc = smem + 8192 + cur * 4096;
    short8 af[2][2], bf[2][2];
#pragma unroll
    for (int mi = 0; mi < 2; ++mi)
#pragma unroll
      for (int kh = 0; kh < 2; ++kh)
        af[mi][kh] = *(const short8*)(Ac + (wm + mi * 16 + ln) * 64 +
                                      ((kh * 4 + g) ^ swz) * 8);
#pragma unroll
    for (int ni = 0; ni < 2; ++ni)
#pragma unroll
      for (int kh = 0; kh < 2; ++kh)
        bf[ni][kh] = *(const short8*)(Bc + (wn + ni * 16 + ln) * 64 +
                                      ((kh * 4 + g) ^ swz) * 8);
#pragma unroll
    for (int kh = 0; kh < 2; ++kh)
#pragma unroll
      for (int mi = 0; mi < 2; ++mi)
#pragma unroll
        for (int ni = 0; ni < 2; ++ni)
          acc[mi][ni] = __builtin_amdgcn_mfma_f32_16x16x32_bf16(
              af[mi][kh], bf[ni][kh], acc[mi][ni], 0, 0, 0);
  }

#pragma unroll
  for (int mi = 0; mi < 2; ++mi) {
    int row = m0 + wm + mi * 16 + g * 4;
#pragma unroll
    for (int ni = 0; ni < 2; ++ni) {
      int col = n0 + wn + ni * 16 + ln;
      float b = bo[col];
#pragma unroll
      for (int r = 0; r < 4; ++r)
        Cout[(size_t)(row + r) * DM + col] = acc[mi][ni][r] + b;
    }
  }
}

extern "C" void kernel_launch(void* const* d_in, const int* in_sizes, int n_in,
                              void* d_out, int out_size, void* d_ws, size_t ws_size,
                              hipStream_t stream) {
  const float* X  = (const float*)d_in[0];
  const float* Wq = (const float*)d_in[1];
  const float* bq = (const float*)d_in[2];
  const float* Wk = (const float*)d_in[3];
  const float* bk = (const float*)d_in[4];
  const float* Wv = (const float*)d_in[5];
  const float* bv = (const float*)d_in[6];
  const float* Wo = (const float*)d_in[7];
  const float* bo = (const float*)d_in[8];
  float* out = (float*)d_out;

  // Workspace layout with OVERLAY: Xb/Wqb/Wkb/Wvb are dead after gemm_qkv,
  // so Opart (25.2MB) reuses their region.
  char* ws = (char*)d_ws;
  u16* Wob = (u16*)ws; ws += (size_t)DM * DM * 2;                 // 1.18MB
  u16* Qh  = (u16*)ws; ws += (size_t)NH * SEQ * HD * 2;           // 6.29MB
  u16* Kh  = (u16*)ws; ws += (size_t)NH * SEQ * HD * 2;           // 6.29MB
  u16* VtG = (u16*)ws; ws += (size_t)NH * SEQ * HD * 2;           // [h][d][s]
  u16* Ob  = (u16*)ws; ws += (size_t)SEQ * DM * 2;                // 6.29MB
  float* Lp = (float*)ws; ws += (size_t)NH * 32 * 4 * 128 * 4;    // 0.79MB
  char* ovl = ws;
  u16* Xb  = (u16*)ovl;
  u16* Wqb = Xb + (size_t)SEQ * DM;
  u16* Wkb = Wqb + (size_t)DM * DM;
  u16* Wvb = Wkb + (size_t)DM * DM;
  u16* Opart = (u16*)ovl;   // 12*32*4*128*64*2 = 25.2MB, after Xb/Wq/Wk/Wv die

  convert_all<<<5376, 256, 0, stream>>>(X, Wq, Wk, Wv, Wo, Xb, Wqb, Wkb, Wvb,
                                        Wob);

  gemm_qkv<<<576, 256, 0, stream>>>(Xb, Wqb, Wkb, Wvb, bq, bk, bv, Qh, Kh, VtG);

  dim3 ga(NH, 80);
  attn_chunk<<<ga, 256, 0, stream>>>(Qh, Kh, VtG, Opart, Lp, Ob);

  dim3 gm(NH, 24);
  attn_merge<<<gm, 256, 0, stream>>>(Opart, Lp, Ob);

  dim3 go(DM / 64, SEQ / 64);
  gemm_out<<<go, 256, 0, stream>>>(Ob, Wob, bo, out);
}